// Round 20
// baseline (303.664 us; speedup 1.0000x reference)
//
#include <hip/hip_runtime.h>
#include <hip/hip_bf16.h>
#include <stdint.h>

typedef __attribute__((ext_vector_type(8))) short short8;
typedef __attribute__((ext_vector_type(4))) short short4v;
typedef __attribute__((ext_vector_type(4))) float f32x4;
typedef __attribute__((ext_vector_type(4))) unsigned int uint4v;

static __device__ __forceinline__ ushort f2bf(float f) {
    uint32_t u = __builtin_bit_cast(uint32_t, f);
    uint32_t r = (u + 0x7FFFu + ((u >> 16) & 1u)) >> 16;
    return (ushort)r;
}

static __device__ __forceinline__ uint32_t cvt_pk_bf16(float lo, float hi) {
    uint32_t d;
    asm("v_cvt_pk_bf16_f32 %0, %1, %2" : "=v"(d) : "v"(lo), "v"(hi));
    return d;
}

static __device__ __forceinline__ float max3f(float a, float b, float c) {
    float d;
    asm("v_max3_f32 %0, %1, %2, %3" : "=v"(d) : "v"(a), "v"(b), "v"(c));
    return d;
}

static __device__ __forceinline__ void async_copy16(const void* g, void* l) {
    __builtin_amdgcn_global_load_lds(
        (const __attribute__((address_space(1))) uint32_t*)g,
        (__attribute__((address_space(3))) uint32_t*)l, 16, 0, 0);
}

// ---------------- cast fp32 -> bf16 ----------------
__global__ __launch_bounds__(256) void cast_kernel(const float* __restrict__ in,
                                                   ushort* __restrict__ out, int n4) {
    int i = blockIdx.x * 256 + threadIdx.x;
    if (i >= n4) return;
    float4 v = reinterpret_cast<const float4*>(in)[i];
    uint2 o;
    o.x = cvt_pk_bf16(v.x, v.y);
    o.y = cvt_pk_bf16(v.z, v.w);
    reinterpret_cast<uint2*>(out)[i] = o;
}

// cast 3 equal-size fp32 buffers into one contiguous bf16 region
__global__ __launch_bounds__(256) void cast3_kernel(const float* __restrict__ a,
                                                    const float* __restrict__ b,
                                                    const float* __restrict__ c,
                                                    ushort* __restrict__ out, int n4each) {
    int i = blockIdx.x * 256 + threadIdx.x;
    int which = i / n4each;
    int j = i - which * n4each;
    const float* src = which == 0 ? a : (which == 1 ? b : c);
    if (which > 2) return;
    float4 v = reinterpret_cast<const float4*>(src)[j];
    uint2 o;
    o.x = cvt_pk_bf16(v.x, v.y);
    o.y = cvt_pk_bf16(v.z, v.w);
    reinterpret_cast<uint2*>(out)[i] = o;
}

static __device__ __forceinline__ void store_val(float* C, size_t idx, float v) { C[idx] = v; }
static __device__ __forceinline__ void store_val(ushort* C, size_t idx, float v) { C[idx] = f2bf(v); }

// ---------------- 128-tile pipelined GEMM ----------------
template <typename OutT>
__global__ __launch_bounds__(256) void gemm128p_kernel(const ushort* __restrict__ A,
                                                       const ushort* __restrict__ B,
                                                       OutT* __restrict__ C,
                                                       int M, int N, int K) {
    __shared__ __align__(16) char smem[65536];
    const int tid = threadIdx.x, w = tid >> 6, lane = tid & 63;
    const int fr = lane & 15, fq = lane >> 4;
    const int wr = w >> 1, wc = w & 1;
    const int row0 = blockIdx.y * 128;
    const int col0 = blockIdx.x * 128;

    const int lo = ((tid & 7) ^ ((tid >> 3) & 7)) << 4;
    const int r0p = ((tid >> 3) << 1) + (lo >> 6);
    const int colE = (lo & 63) >> 1;
    const ushort* Ap0 = A + (size_t)(row0 + r0p) * K + colE;
    const ushort* Ap1 = A + (size_t)(row0 + 64 + r0p) * K + colE;
    const ushort* Bp0 = B + (size_t)(col0 + r0p) * K + colE;
    const ushort* Bp1 = B + (size_t)(col0 + 64 + r0p) * K + colE;

    const int wbyte = w * 1024;
    auto stageP = [&](int h) {
        const int kc = h * 32;
        char* ar = smem + (h & 3) * 8192;
        char* br = smem + 32768 + (h & 3) * 8192;
        async_copy16(Ap0 + kc, ar + wbyte);
        async_copy16(Ap1 + kc, ar + 4096 + wbyte);
        async_copy16(Bp0 + kc, br + wbyte);
        async_copy16(Bp1 + kc, br + 4096 + wbyte);
    };

    const int swz = ((fr & 1) * 64 + fq * 16) ^ (((fr >> 1) & 7) << 4);
    const int aBase = (wr * 32 + (fr >> 1)) * 128 + swz;
    const int bBase = (wc * 32 + (fr >> 1)) * 128 + swz;

    f32x4 acc[4][4];
#pragma unroll
    for (int m = 0; m < 4; ++m)
#pragma unroll
        for (int n = 0; n < 4; ++n) acc[m][n] = f32x4{0.f, 0.f, 0.f, 0.f};

    const int nP = K >> 5;
    stageP(0); stageP(1); stageP(2);
    asm volatile("s_waitcnt vmcnt(8)\n\ts_barrier" ::: "memory");

    for (int i = 0; i < nP; ++i) {
        if (i + 3 < nP) stageP(i + 3);
        const char* ar = smem + (i & 3) * 8192 + aBase;
        const char* br = smem + 32768 + (i & 3) * 8192 + bBase;
        short8 af[4], bf[4];
#pragma unroll
        for (int m = 0; m < 4; ++m) af[m] = *(const short8*)(ar + m * 1024);
#pragma unroll
        for (int n = 0; n < 4; ++n) bf[n] = *(const short8*)(br + n * 1024);
        __builtin_amdgcn_s_setprio(1);
#pragma unroll
        for (int m = 0; m < 4; ++m)
#pragma unroll
            for (int n = 0; n < 4; ++n)
                acc[m][n] = __builtin_amdgcn_mfma_f32_16x16x32_bf16(af[m], bf[n], acc[m][n], 0, 0, 0);
        __builtin_amdgcn_s_setprio(0);
        if (i < nP - 3)
            asm volatile("s_waitcnt vmcnt(8)\n\ts_barrier" ::: "memory");
        else if (i == nP - 3)
            asm volatile("s_waitcnt vmcnt(4)\n\ts_barrier" ::: "memory");
        else if (i == nP - 2)
            asm volatile("s_waitcnt vmcnt(0)\n\ts_barrier" ::: "memory");
    }

#pragma unroll
    for (int m = 0; m < 4; ++m) {
        const int grow = row0 + wr * 64 + m * 16 + fq * 4;
#pragma unroll
        for (int n = 0; n < 4; ++n) {
            const int gcol = col0 + wc * 64 + n * 16 + fr;
#pragma unroll
            for (int r = 0; r < 4; ++r)
                store_val(C, (size_t)(grow + r) * N + gcol, acc[m][n][r]);
        }
    }
}

// ---------------- 256-tile pipelined GEMM (R18 schedule; bf16 out) ----------------
__global__ __launch_bounds__(512, 2) void gemm256_kernel(const ushort* __restrict__ A,
                                                         const ushort* __restrict__ B,
                                                         ushort* __restrict__ C,
                                                         int M, int N, int K, float qscale) {
    __shared__ __align__(16) char smem[131072];
    const int tid = threadIdx.x, w = tid >> 6, lane = tid & 63;
    const int fr = lane & 15, fq = lane >> 4;
    const int wm = w >> 2, wn = w & 3;
    const int bpn = N >> 8;
    const int which = blockIdx.x / bpn;
    const int row0 = blockIdx.y * 256;
    const int gcol0 = blockIdx.x * 256;
    const int col0 = gcol0 - which * N;
    ushort* Cw = C + (size_t)which * M * N;
    const float cs = (which == 0) ? qscale : 1.0f;

    const int lo = ((tid & 7) ^ ((tid >> 3) & 7)) << 4;
    const int r0p = ((tid >> 3) << 1) + (lo >> 6);
    const int colE = (lo & 63) >> 1;
    const ushort* Ap0 = A + (size_t)(row0 + r0p) * K + colE;
    const ushort* Ap1 = A + (size_t)(row0 + 128 + r0p) * K + colE;
    const ushort* Bp0 = B + (size_t)(gcol0 + r0p) * K + colE;
    const ushort* Bp1 = B + (size_t)(gcol0 + 128 + r0p) * K + colE;

    char* aregs = smem;
    char* bregs = smem + 65536;
    const int wbyte = w * 1024;

    auto stageH = [&](int h) {
        const int kc = h * 32;
        char* ar = aregs + (h & 3) * 16384;
        char* br = bregs + (h & 3) * 16384;
        async_copy16(Ap0 + kc, ar + wbyte);
        async_copy16(Ap1 + kc, ar + 8192 + wbyte);
        async_copy16(Bp0 + kc, br + wbyte);
        async_copy16(Bp1 + kc, br + 8192 + wbyte);
    };

    const int swz = ((fr & 1) * 64 + fq * 16) ^ (((fr >> 1) & 7) << 4);
    const int aBase = (wm * 64 + (fr >> 1)) * 128 + swz;
    const int bBase = (wn * 32 + (fr >> 1)) * 128 + swz;

    f32x4 acc[8][4];
#pragma unroll
    for (int m = 0; m < 8; ++m)
#pragma unroll
        for (int n = 0; n < 4; ++n) acc[m][n] = f32x4{0.f, 0.f, 0.f, 0.f};

    const int nH = K >> 5;
    stageH(0); stageH(1); stageH(2);
    asm volatile("s_waitcnt vmcnt(8)\n\ts_barrier" ::: "memory");

    for (int i = 0; i < nH; ++i) {
        if (i + 3 < nH) stageH(i + 3);
        const char* ar = aregs + (i & 3) * 16384 + aBase;
        const char* br = bregs + (i & 3) * 16384 + bBase;
        short8 af[8], bf[4];
#pragma unroll
        for (int m = 0; m < 8; ++m) af[m] = *(const short8*)(ar + m * 1024);
#pragma unroll
        for (int n = 0; n < 4; ++n) bf[n] = *(const short8*)(br + n * 1024);
        __builtin_amdgcn_s_setprio(1);
#pragma unroll
        for (int m = 0; m < 8; ++m)
#pragma unroll
            for (int n = 0; n < 4; ++n)
                acc[m][n] = __builtin_amdgcn_mfma_f32_16x16x32_bf16(af[m], bf[n], acc[m][n], 0, 0, 0);
        __builtin_amdgcn_s_setprio(0);
        if (i < nH - 3)
            asm volatile("s_waitcnt vmcnt(8)\n\ts_barrier" ::: "memory");
        else if (i == nH - 3)
            asm volatile("s_waitcnt vmcnt(4)\n\ts_barrier" ::: "memory");
        else if (i == nH - 2)
            asm volatile("s_waitcnt vmcnt(0)\n\ts_barrier" ::: "memory");
    }

#pragma unroll
    for (int m = 0; m < 8; ++m) {
        const int grow = row0 + wm * 128 + m * 16 + fq * 4;
#pragma unroll
        for (int n = 0; n < 4; ++n) {
            const int gcol = col0 + wn * 64 + n * 16 + fr;
#pragma unroll
            for (int r2 = 0; r2 < 4; ++r2)
                Cw[(size_t)(grow + r2) * N + gcol] = f2bf(acc[m][n][r2] * cs);
        }
    }
}

// ---------------- flash attention fwd ----------------
// R17 base + zero-shuffle PV: the MFMA k-order over kv is permuted
// (position (kvc,fq,e) <-> kv = kvc*32+(e>>2)*16+fq*4+(e&3)) so the
// P B-operand is lane-local (pf = cpk[2kvc]||cpk[2kvc+1], no shfl) and
// vf = two ds_read_b64 per frag from the unchanged Vts layout.
__global__ __launch_bounds__(512) void attn_kernel(const ushort* __restrict__ Q,
                                                   const ushort* __restrict__ K,
                                                   const ushort* __restrict__ VT,
                                                   ushort* __restrict__ O,
                                                   int S, int HID) {
    __shared__ __align__(16) ushort Ks[2][64 * 128];    // swz: byte ^= ((row&7)<<4)
    __shared__ __align__(16) ushort Vts[2][128 * 64];   // [dh][kv], same swz

    const int tid = threadIdx.x, w = tid >> 6, lane = tid & 63;
    const int fr = lane & 15, fq = lane >> 4;
    const int h = blockIdx.x & 15, b = blockIdx.x >> 4, qt = blockIdx.y;
    const size_t rs = (size_t)HID;
    const size_t vs = (size_t)(2 * S);
    const int qr0 = qt * 128 + w * 16;

    short8 qf[4];
    {
        const ushort* qp = Q + ((size_t)(b * S) + qr0 + fr) * rs + h * 128 + fq * 8;
#pragma unroll
        for (int ks = 0; ks < 4; ++ks) qf[ks] = *(const short8*)(qp + ks * 32);
    }

    f32x4 of[8];
#pragma unroll
    for (int n = 0; n < 8; ++n) of[n] = f32x4{0.f, 0.f, 0.f, 0.f};
    float m2 = -1e30f;
    float l = 0.f;

    const ushort* Kb = K + (size_t)(b * S) * rs + h * 128;
    const ushort* Vb = VT + (size_t)(h * 128) * vs + b * S;

    size_t koff[2];
#pragma unroll
    for (int j = 0; j < 2; ++j) {
        int row = j * 32 + w * 4 + (lane >> 4);
        int colb = ((lane & 15) * 16) ^ ((row & 7) << 4);
        koff[j] = (size_t)row * rs + (colb >> 1);
    }
    size_t vtoff[2];
#pragma unroll
    for (int j = 0; j < 2; ++j) {
        int row = j * 64 + (tid >> 3);
        int colb = ((tid & 7) * 16) ^ ((row & 7) << 4);
        vtoff[j] = (size_t)row * vs + (colb >> 1);
    }

    auto stage = [&](int t) {
        const int bufb = t & 1;
        const ushort* kt0 = Kb + (size_t)t * 64 * rs;
        const ushort* vt0 = Vb + (size_t)t * 64;
#pragma unroll
        for (int j = 0; j < 2; ++j)
            async_copy16(kt0 + koff[j], &Ks[bufb][j * 4096 + w * 512]);
#pragma unroll
        for (int j = 0; j < 2; ++j)
            async_copy16(vt0 + vtoff[j], &Vts[bufb][j * 4096 + w * 512]);
    };

    const int nt = S / 64;
    stage(0);
    for (int t = 0; t < nt; ++t) {
        __builtin_amdgcn_s_barrier();
        __builtin_amdgcn_sched_barrier(0);
        if (t + 1 < nt) {
            stage(t + 1);
            asm volatile("s_waitcnt vmcnt(4)" ::: "memory");
        } else {
            asm volatile("s_waitcnt vmcnt(0)" ::: "memory");
        }
        __builtin_amdgcn_s_barrier();
        __builtin_amdgcn_sched_barrier(0);

        const char* kbase = (const char*)&Ks[t & 1][0];
        const char* vbase = (const char*)&Vts[t & 1][0];

        // ---- S^T = K Q^T : lane holds S[kv=kc*16+fq*4+r][q=fr] (log2 dom) ----
        f32x4 sf[4];
        __builtin_amdgcn_s_setprio(1);
#pragma unroll
        for (int kc = 0; kc < 4; ++kc) {
            f32x4 s = f32x4{0.f, 0.f, 0.f, 0.f};
#pragma unroll
            for (int ks = 0; ks < 4; ++ks) {
                int row = kc * 16 + fr;
                int pb = (row * 256 + ks * 64 + fq * 16) ^ ((row & 7) << 4);
                short8 kf = *(const short8*)(kbase + pb);
                s = __builtin_amdgcn_mfma_f32_16x16x32_bf16(kf, qf[ks], s, 0, 0, 0);
            }
            sf[kc] = s;
        }
        __builtin_amdgcn_s_setprio(0);

        // ---- online softmax, lane-local (q = fr), defer-max THR=8 ----
        float pm = max3f(sf[0][0], sf[0][1], sf[0][2]);
        pm = max3f(pm, sf[0][3], sf[1][0]);
        pm = max3f(pm, sf[1][1], sf[1][2]);
        pm = max3f(pm, sf[1][3], sf[2][0]);
        pm = max3f(pm, sf[2][1], sf[2][2]);
        pm = max3f(pm, sf[2][3], sf[3][0]);
        pm = max3f(pm, sf[3][1], sf[3][2]);
        pm = fmaxf(pm, sf[3][3]);
        pm = fmaxf(pm, __shfl_xor(pm, 16));
        pm = fmaxf(pm, __shfl_xor(pm, 32));
        const bool noresc = __all(pm - m2 <= 8.0f);
        float sc = 1.0f;
        if (!noresc) {
            float m2new = fmaxf(m2, pm);
            sc = exp2f(m2 - m2new);
            m2 = m2new;
        }
        float rsum = 0.f;
#pragma unroll
        for (int kc = 0; kc < 4; ++kc)
#pragma unroll
            for (int r = 0; r < 4; ++r) {
                float p = exp2f(sf[kc][r] - m2);
                sf[kc][r] = p;
                rsum += p;
            }
        rsum += __shfl_xor(rsum, 16);
        rsum += __shfl_xor(rsum, 32);
        if (noresc) {
            l = l + rsum;
        } else {
            l = l * sc + rsum;
#pragma unroll
            for (int n = 0; n < 8; ++n) {
                f32x4 o = of[n];
                o[0] *= sc; o[1] *= sc; o[2] *= sc; o[3] *= sc;
                of[n] = o;
            }
        }

        // ---- pack P pairs to bf16 dwords (lane-local) ----
        uint32_t cpk[4][2];
#pragma unroll
        for (int kc = 0; kc < 4; ++kc)
#pragma unroll
            for (int hh = 0; hh < 2; ++hh)
                cpk[kc][hh] = cvt_pk_bf16(sf[kc][2 * hh], sf[kc][2 * hh + 1]);

        // ---- O^T += V^T P : permuted-k, zero-shuffle pf; vf = 2x ds_read_b64 ----
        __builtin_amdgcn_s_setprio(1);
#pragma unroll
        for (int kvc = 0; kvc < 2; ++kvc) {
            uint4v pd;
            pd[0] = cpk[2 * kvc][0];
            pd[1] = cpk[2 * kvc][1];
            pd[2] = cpk[2 * kvc + 1][0];
            pd[3] = cpk[2 * kvc + 1][1];
            short8 pf = __builtin_bit_cast(short8, pd);
#pragma unroll
            for (int n = 0; n < 8; ++n) {
                int row = n * 16 + fr;
                int s = (row & 7) << 4;
                int b1 = row * 128 + ((kvc * 64 + fq * 8) ^ s);
                int b2 = row * 128 + ((kvc * 64 + 32 + fq * 8) ^ s);
                short4v vlo = *(const short4v*)(vbase + b1);
                short4v vhi = *(const short4v*)(vbase + b2);
                short8 vf = __builtin_shufflevector(vlo, vhi, 0, 1, 2, 3, 4, 5, 6, 7);
                of[n] = __builtin_amdgcn_mfma_f32_16x16x32_bf16(vf, pf, of[n], 0, 0, 0);
            }
        }
        __builtin_amdgcn_s_setprio(0);
    }

    // ---- epilogue: lane owns q=qr0+fr; of[n][r] = O[q][dh=n*16+fq*4+r] ----
    float inv = 1.f / l;
    ushort* ob = O + ((size_t)(b * S) + qr0 + fr) * rs + h * 128 + fq * 4;
#pragma unroll
    for (int n = 0; n < 8; ++n) {
        uint2 o2;
        o2.x = cvt_pk_bf16(of[n][0] * inv, of[n][1] * inv);
        o2.y = cvt_pk_bf16(of[n][2] * inv, of[n][3] * inv);
        *reinterpret_cast<uint2*>(ob + n * 16) = o2;
    }
}

// ---------------- launch ----------------
extern "C" void kernel_launch(void* const* d_in, const int* in_sizes, int n_in,
                              void* d_out, int out_size, void* d_ws, size_t ws_size,
                              hipStream_t stream) {
    constexpr int B = 2, S = 2048, HID = 2048, H = 16;
    constexpr int M = B * S;
    const float qscale = 0.08838834764831845f * 1.4426950408889634f;  // scale*log2e

    const float* x  = (const float*)d_in[0];
    const float* wq = (const float*)d_in[1];
    const float* wk = (const float*)d_in[2];
    const float* wv = (const float*)d_in[3];
    const float* wo = (const float*)d_in[4];
    float* out = (float*)d_out;

    char* ws = (char*)d_ws;
    ushort* xb  = (ushort*)(ws);                    // [4096][2048] bf16; reused as attn out
    ushort* wqb = (ushort*)(ws + 16777216);         // wq,wk,wv casts contiguous (24 MB)
    ushort* wvb = (ushort*)(ws + 33554432);
    ushort* qb  = (ushort*)(ws + 41943040);         // q,k contiguous (32 MB)
    ushort* kb  = (ushort*)(ws + 58720256);
    ushort* vtb = (ushort*)(ws + 75497472);         // V^T [2048][4096] (16 MB)

    const int XN = M * HID;
    const int WN = HID * HID;

    cast_kernel<<<XN / 4 / 256, 256, 0, stream>>>(x, xb, XN / 4);
    cast3_kernel<<<3 * WN / 4 / 256, 256, 0, stream>>>(wq, wk, wv, wqb, WN / 4);

    // Q,K projection: pipelined 256-tile GEMM; Q pre-scaled by scale*log2e
    dim3 gq(2 * HID / 256, M / 256);   // (16, 16) = 256 blocks x 512 threads
    gemm256_kernel<<<gq, 512, 0, stream>>>(xb, wqb, qb, M, HID, HID, qscale);

    // V^T projection via pipelined 128-tile GEMM
    dim3 gv(M / 128, HID / 128);       // (32, 16) = 512 blocks x 256 threads
    gemm128p_kernel<ushort><<<gv, 256, 0, stream>>>(wvb, xb, vtb, HID, M, HID);

    dim3 ga(H * B, S / 128);           // (32, 16) = 512 blocks x 512 threads
    attn_kernel<<<ga, 512, 0, stream>>>(qb, kb, vtb, xb, S, HID);

    cast_kernel<<<WN / 4 / 256, 256, 0, stream>>>(wo, wqb, WN / 4);
    dim3 gg(HID / 128, M / 128);       // (16, 32) = 512 blocks x 256 threads
    gemm128p_kernel<float><<<gg, 256, 0, stream>>>(xb, wqb, out, M, HID, HID);
}

// Round 21
// 294.440 us; speedup vs baseline: 1.0313x; 1.0313x over previous
//
#include <hip/hip_runtime.h>
#include <hip/hip_bf16.h>
#include <stdint.h>

typedef __attribute__((ext_vector_type(8))) short short8;
typedef __attribute__((ext_vector_type(4))) float f32x4;
typedef __attribute__((ext_vector_type(4))) unsigned int uint4v;

static __device__ __forceinline__ ushort f2bf(float f) {
    uint32_t u = __builtin_bit_cast(uint32_t, f);
    uint32_t r = (u + 0x7FFFu + ((u >> 16) & 1u)) >> 16;
    return (ushort)r;
}

static __device__ __forceinline__ uint32_t cvt_pk_bf16(float lo, float hi) {
    uint32_t d;
    asm("v_cvt_pk_bf16_f32 %0, %1, %2" : "=v"(d) : "v"(lo), "v"(hi));
    return d;
}

static __device__ __forceinline__ float max3f(float a, float b, float c) {
    float d;
    asm("v_max3_f32 %0, %1, %2, %3" : "=v"(d) : "v"(a), "v"(b), "v"(c));
    return d;
}

static __device__ __forceinline__ void async_copy16(const void* g, void* l) {
    __builtin_amdgcn_global_load_lds(
        (const __attribute__((address_space(1))) uint32_t*)g,
        (__attribute__((address_space(3))) uint32_t*)l, 16, 0, 0);
}

// ---------------- cast fp32 -> bf16 ----------------
__global__ __launch_bounds__(256) void cast_kernel(const float* __restrict__ in,
                                                   ushort* __restrict__ out, int n4) {
    int i = blockIdx.x * 256 + threadIdx.x;
    if (i >= n4) return;
    float4 v = reinterpret_cast<const float4*>(in)[i];
    uint2 o;
    o.x = cvt_pk_bf16(v.x, v.y);
    o.y = cvt_pk_bf16(v.z, v.w);
    reinterpret_cast<uint2*>(out)[i] = o;
}

// fused cast: x (n4x quads) -> outx, then wq,wk,wv (n4w quads each) -> outw contiguous
__global__ __launch_bounds__(256) void cast4_kernel(const float* __restrict__ x,
                                                    const float* __restrict__ a,
                                                    const float* __restrict__ b,
                                                    const float* __restrict__ c,
                                                    ushort* __restrict__ outx,
                                                    ushort* __restrict__ outw,
                                                    int n4x, int n4w) {
    int i = blockIdx.x * 256 + threadIdx.x;
    const float* src;
    ushort* dst;
    int j;
    if (i < n4x) {
        src = x; dst = outx; j = i;
    } else {
        int k = i - n4x;
        int which = k / n4w;
        j = k - which * n4w;
        src = which == 0 ? a : (which == 1 ? b : c);
        dst = outw + (size_t)which * n4w * 4;
        if (which > 2) return;
    }
    float4 v = reinterpret_cast<const float4*>(src)[j];
    uint2 o;
    o.x = cvt_pk_bf16(v.x, v.y);
    o.y = cvt_pk_bf16(v.z, v.w);
    reinterpret_cast<uint2*>(dst)[j] = o;
}

static __device__ __forceinline__ void store_val(float* C, size_t idx, float v) { C[idx] = v; }
static __device__ __forceinline__ void store_val(ushort* C, size_t idx, float v) { C[idx] = f2bf(v); }

// ---------------- 128-tile pipelined GEMM ----------------
template <typename OutT>
__global__ __launch_bounds__(256) void gemm128p_kernel(const ushort* __restrict__ A,
                                                       const ushort* __restrict__ B,
                                                       OutT* __restrict__ C,
                                                       int M, int N, int K) {
    __shared__ __align__(16) char smem[65536];
    const int tid = threadIdx.x, w = tid >> 6, lane = tid & 63;
    const int fr = lane & 15, fq = lane >> 4;
    const int wr = w >> 1, wc = w & 1;
    const int row0 = blockIdx.y * 128;
    const int col0 = blockIdx.x * 128;

    const int lo = ((tid & 7) ^ ((tid >> 3) & 7)) << 4;
    const int r0p = ((tid >> 3) << 1) + (lo >> 6);
    const int colE = (lo & 63) >> 1;
    const ushort* Ap0 = A + (size_t)(row0 + r0p) * K + colE;
    const ushort* Ap1 = A + (size_t)(row0 + 64 + r0p) * K + colE;
    const ushort* Bp0 = B + (size_t)(col0 + r0p) * K + colE;
    const ushort* Bp1 = B + (size_t)(col0 + 64 + r0p) * K + colE;

    const int wbyte = w * 1024;
    auto stageP = [&](int h) {
        const int kc = h * 32;
        char* ar = smem + (h & 3) * 8192;
        char* br = smem + 32768 + (h & 3) * 8192;
        async_copy16(Ap0 + kc, ar + wbyte);
        async_copy16(Ap1 + kc, ar + 4096 + wbyte);
        async_copy16(Bp0 + kc, br + wbyte);
        async_copy16(Bp1 + kc, br + 4096 + wbyte);
    };

    const int swz = ((fr & 1) * 64 + fq * 16) ^ (((fr >> 1) & 7) << 4);
    const int aBase = (wr * 32 + (fr >> 1)) * 128 + swz;
    const int bBase = (wc * 32 + (fr >> 1)) * 128 + swz;

    f32x4 acc[4][4];
#pragma unroll
    for (int m = 0; m < 4; ++m)
#pragma unroll
        for (int n = 0; n < 4; ++n) acc[m][n] = f32x4{0.f, 0.f, 0.f, 0.f};

    const int nP = K >> 5;
    stageP(0); stageP(1); stageP(2);
    asm volatile("s_waitcnt vmcnt(8)\n\ts_barrier" ::: "memory");

    for (int i = 0; i < nP; ++i) {
        if (i + 3 < nP) stageP(i + 3);
        const char* ar = smem + (i & 3) * 8192 + aBase;
        const char* br = smem + 32768 + (i & 3) * 8192 + bBase;
        short8 af[4], bf[4];
#pragma unroll
        for (int m = 0; m < 4; ++m) af[m] = *(const short8*)(ar + m * 1024);
#pragma unroll
        for (int n = 0; n < 4; ++n) bf[n] = *(const short8*)(br + n * 1024);
        __builtin_amdgcn_s_setprio(1);
#pragma unroll
        for (int m = 0; m < 4; ++m)
#pragma unroll
            for (int n = 0; n < 4; ++n)
                acc[m][n] = __builtin_amdgcn_mfma_f32_16x16x32_bf16(af[m], bf[n], acc[m][n], 0, 0, 0);
        __builtin_amdgcn_s_setprio(0);
        if (i < nP - 3)
            asm volatile("s_waitcnt vmcnt(8)\n\ts_barrier" ::: "memory");
        else if (i == nP - 3)
            asm volatile("s_waitcnt vmcnt(4)\n\ts_barrier" ::: "memory");
        else if (i == nP - 2)
            asm volatile("s_waitcnt vmcnt(0)\n\ts_barrier" ::: "memory");
    }

#pragma unroll
    for (int m = 0; m < 4; ++m) {
        const int grow = row0 + wr * 64 + m * 16 + fq * 4;
#pragma unroll
        for (int n = 0; n < 4; ++n) {
            const int gcol = col0 + wc * 64 + n * 16 + fr;
#pragma unroll
            for (int r = 0; r < 4; ++r)
                store_val(C, (size_t)(grow + r) * N + gcol, acc[m][n][r]);
        }
    }
}

// ---------------- 256-tile pipelined GEMM (R18 schedule; bf16 out) ----------------
__global__ __launch_bounds__(512, 2) void gemm256_kernel(const ushort* __restrict__ A,
                                                         const ushort* __restrict__ B,
                                                         ushort* __restrict__ C,
                                                         int M, int N, int K, float qscale) {
    __shared__ __align__(16) char smem[131072];
    const int tid = threadIdx.x, w = tid >> 6, lane = tid & 63;
    const int fr = lane & 15, fq = lane >> 4;
    const int wm = w >> 2, wn = w & 3;
    const int bpn = N >> 8;
    const int which = blockIdx.x / bpn;
    const int row0 = blockIdx.y * 256;
    const int gcol0 = blockIdx.x * 256;
    const int col0 = gcol0 - which * N;
    ushort* Cw = C + (size_t)which * M * N;
    const float cs = (which == 0) ? qscale : 1.0f;

    const int lo = ((tid & 7) ^ ((tid >> 3) & 7)) << 4;
    const int r0p = ((tid >> 3) << 1) + (lo >> 6);
    const int colE = (lo & 63) >> 1;
    const ushort* Ap0 = A + (size_t)(row0 + r0p) * K + colE;
    const ushort* Ap1 = A + (size_t)(row0 + 128 + r0p) * K + colE;
    const ushort* Bp0 = B + (size_t)(gcol0 + r0p) * K + colE;
    const ushort* Bp1 = B + (size_t)(gcol0 + 128 + r0p) * K + colE;

    char* aregs = smem;
    char* bregs = smem + 65536;
    const int wbyte = w * 1024;

    auto stageH = [&](int h) {
        const int kc = h * 32;
        char* ar = aregs + (h & 3) * 16384;
        char* br = bregs + (h & 3) * 16384;
        async_copy16(Ap0 + kc, ar + wbyte);
        async_copy16(Ap1 + kc, ar + 8192 + wbyte);
        async_copy16(Bp0 + kc, br + wbyte);
        async_copy16(Bp1 + kc, br + 8192 + wbyte);
    };

    const int swz = ((fr & 1) * 64 + fq * 16) ^ (((fr >> 1) & 7) << 4);
    const int aBase = (wm * 64 + (fr >> 1)) * 128 + swz;
    const int bBase = (wn * 32 + (fr >> 1)) * 128 + swz;

    f32x4 acc[8][4];
#pragma unroll
    for (int m = 0; m < 8; ++m)
#pragma unroll
        for (int n = 0; n < 4; ++n) acc[m][n] = f32x4{0.f, 0.f, 0.f, 0.f};

    const int nH = K >> 5;
    stageH(0); stageH(1); stageH(2);
    asm volatile("s_waitcnt vmcnt(8)\n\ts_barrier" ::: "memory");

    for (int i = 0; i < nH; ++i) {
        if (i + 3 < nH) stageH(i + 3);
        const char* ar = aregs + (i & 3) * 16384 + aBase;
        const char* br = bregs + (i & 3) * 16384 + bBase;
        short8 af[8], bf[4];
#pragma unroll
        for (int m = 0; m < 8; ++m) af[m] = *(const short8*)(ar + m * 1024);
#pragma unroll
        for (int n = 0; n < 4; ++n) bf[n] = *(const short8*)(br + n * 1024);
        __builtin_amdgcn_s_setprio(1);
#pragma unroll
        for (int m = 0; m < 8; ++m)
#pragma unroll
            for (int n = 0; n < 4; ++n)
                acc[m][n] = __builtin_amdgcn_mfma_f32_16x16x32_bf16(af[m], bf[n], acc[m][n], 0, 0, 0);
        __builtin_amdgcn_s_setprio(0);
        if (i < nH - 3)
            asm volatile("s_waitcnt vmcnt(8)\n\ts_barrier" ::: "memory");
        else if (i == nH - 3)
            asm volatile("s_waitcnt vmcnt(4)\n\ts_barrier" ::: "memory");
        else if (i == nH - 2)
            asm volatile("s_waitcnt vmcnt(0)\n\ts_barrier" ::: "memory");
    }

#pragma unroll
    for (int m = 0; m < 8; ++m) {
        const int grow = row0 + wm * 128 + m * 16 + fq * 4;
#pragma unroll
        for (int n = 0; n < 4; ++n) {
            const int gcol = col0 + wn * 64 + n * 16 + fr;
#pragma unroll
            for (int r2 = 0; r2 < 4; ++r2)
                Cw[(size_t)(grow + r2) * N + gcol] = f2bf(acc[m][n][r2] * cs);
        }
    }
}

// ---------------- flash attention fwd (R18/R17 structure — best measured) ----------------
__global__ __launch_bounds__(512) void attn_kernel(const ushort* __restrict__ Q,
                                                   const ushort* __restrict__ K,
                                                   const ushort* __restrict__ VT,
                                                   ushort* __restrict__ O,
                                                   int S, int HID) {
    __shared__ __align__(16) ushort Ks[2][64 * 128];    // swz: byte ^= ((row&7)<<4)
    __shared__ __align__(16) ushort Vts[2][128 * 64];   // [dh][kv], same swz

    const int tid = threadIdx.x, w = tid >> 6, lane = tid & 63;
    const int fr = lane & 15, fq = lane >> 4;
    const int h = blockIdx.x & 15, b = blockIdx.x >> 4, qt = blockIdx.y;
    const size_t rs = (size_t)HID;
    const size_t vs = (size_t)(2 * S);
    const int qr0 = qt * 128 + w * 16;

    short8 qf[4];
    {
        const ushort* qp = Q + ((size_t)(b * S) + qr0 + fr) * rs + h * 128 + fq * 8;
#pragma unroll
        for (int ks = 0; ks < 4; ++ks) qf[ks] = *(const short8*)(qp + ks * 32);
    }

    f32x4 of[8];
#pragma unroll
    for (int n = 0; n < 8; ++n) of[n] = f32x4{0.f, 0.f, 0.f, 0.f};
    float m2 = -1e30f;
    float l = 0.f;

    const ushort* Kb = K + (size_t)(b * S) * rs + h * 128;
    const ushort* Vb = VT + (size_t)(h * 128) * vs + b * S;

    size_t koff[2];
#pragma unroll
    for (int j = 0; j < 2; ++j) {
        int row = j * 32 + w * 4 + (lane >> 4);
        int colb = ((lane & 15) * 16) ^ ((row & 7) << 4);
        koff[j] = (size_t)row * rs + (colb >> 1);
    }
    size_t vtoff[2];
#pragma unroll
    for (int j = 0; j < 2; ++j) {
        int row = j * 64 + (tid >> 3);
        int colb = ((tid & 7) * 16) ^ ((row & 7) << 4);
        vtoff[j] = (size_t)row * vs + (colb >> 1);
    }

    auto stage = [&](int t) {
        const int bufb = t & 1;
        const ushort* kt0 = Kb + (size_t)t * 64 * rs;
        const ushort* vt0 = Vb + (size_t)t * 64;
#pragma unroll
        for (int j = 0; j < 2; ++j)
            async_copy16(kt0 + koff[j], &Ks[bufb][j * 4096 + w * 512]);
#pragma unroll
        for (int j = 0; j < 2; ++j)
            async_copy16(vt0 + vtoff[j], &Vts[bufb][j * 4096 + w * 512]);
    };

    const int srcA = fr + 16 * ((2 * fq) & 3);
    const int srcB = fr + 16 * ((2 * fq + 1) & 3);
    const int par = fq >> 1;

    const int nt = S / 64;
    stage(0);
    for (int t = 0; t < nt; ++t) {
        __builtin_amdgcn_s_barrier();
        __builtin_amdgcn_sched_barrier(0);
        if (t + 1 < nt) {
            stage(t + 1);
            asm volatile("s_waitcnt vmcnt(4)" ::: "memory");
        } else {
            asm volatile("s_waitcnt vmcnt(0)" ::: "memory");
        }
        __builtin_amdgcn_s_barrier();
        __builtin_amdgcn_sched_barrier(0);

        const char* kbase = (const char*)&Ks[t & 1][0];
        const char* vbase = (const char*)&Vts[t & 1][0];

        f32x4 sf[4];
        __builtin_amdgcn_s_setprio(1);
#pragma unroll
        for (int kc = 0; kc < 4; ++kc) {
            f32x4 s = f32x4{0.f, 0.f, 0.f, 0.f};
#pragma unroll
            for (int ks = 0; ks < 4; ++ks) {
                int row = kc * 16 + fr;
                int pb = (row * 256 + ks * 64 + fq * 16) ^ ((row & 7) << 4);
                short8 kf = *(const short8*)(kbase + pb);
                s = __builtin_amdgcn_mfma_f32_16x16x32_bf16(kf, qf[ks], s, 0, 0, 0);
            }
            sf[kc] = s;
        }
        __builtin_amdgcn_s_setprio(0);

        float pm = max3f(sf[0][0], sf[0][1], sf[0][2]);
        pm = max3f(pm, sf[0][3], sf[1][0]);
        pm = max3f(pm, sf[1][1], sf[1][2]);
        pm = max3f(pm, sf[1][3], sf[2][0]);
        pm = max3f(pm, sf[2][1], sf[2][2]);
        pm = max3f(pm, sf[2][3], sf[3][0]);
        pm = max3f(pm, sf[3][1], sf[3][2]);
        pm = fmaxf(pm, sf[3][3]);
        pm = fmaxf(pm, __shfl_xor(pm, 16));
        pm = fmaxf(pm, __shfl_xor(pm, 32));
        const bool noresc = __all(pm - m2 <= 8.0f);
        float sc = 1.0f;
        if (!noresc) {
            float m2new = fmaxf(m2, pm);
            sc = exp2f(m2 - m2new);
            m2 = m2new;
        }
        float rsum = 0.f;
#pragma unroll
        for (int kc = 0; kc < 4; ++kc)
#pragma unroll
            for (int r = 0; r < 4; ++r) {
                float p = exp2f(sf[kc][r] - m2);
                sf[kc][r] = p;
                rsum += p;
            }
        rsum += __shfl_xor(rsum, 16);
        rsum += __shfl_xor(rsum, 32);
        if (noresc) {
            l = l + rsum;
        } else {
            l = l * sc + rsum;
#pragma unroll
            for (int n = 0; n < 8; ++n) {
                f32x4 o = of[n];
                o[0] *= sc; o[1] *= sc; o[2] *= sc; o[3] *= sc;
                of[n] = o;
            }
        }

        uint32_t cpk[4][2];
#pragma unroll
        for (int kc = 0; kc < 4; ++kc)
#pragma unroll
            for (int hh = 0; hh < 2; ++hh)
                cpk[kc][hh] = cvt_pk_bf16(sf[kc][2 * hh], sf[kc][2 * hh + 1]);

        __builtin_amdgcn_s_setprio(1);
#pragma unroll
        for (int kvc = 0; kvc < 2; ++kvc) {
            uint32_t eA0 = __shfl(cpk[2 * kvc][0], srcA), eA1 = __shfl(cpk[2 * kvc][1], srcA);
            uint32_t oA0 = __shfl(cpk[2 * kvc + 1][0], srcA), oA1 = __shfl(cpk[2 * kvc + 1][1], srcA);
            uint32_t eB0 = __shfl(cpk[2 * kvc][0], srcB), eB1 = __shfl(cpk[2 * kvc][1], srcB);
            uint32_t oB0 = __shfl(cpk[2 * kvc + 1][0], srcB), oB1 = __shfl(cpk[2 * kvc + 1][1], srcB);
            uint4v pd;
            pd[0] = par ? oA0 : eA0; pd[1] = par ? oA1 : eA1;
            pd[2] = par ? oB0 : eB0; pd[3] = par ? oB1 : eB1;
            short8 pf = __builtin_bit_cast(short8, pd);
#pragma unroll
            for (int n = 0; n < 8; ++n) {
                int row = n * 16 + fr;
                int pb = row * 128 + ((kvc * 64 + fq * 16) ^ ((row & 7) << 4));
                short8 vf = *(const short8*)(vbase + pb);
                of[n] = __builtin_amdgcn_mfma_f32_16x16x32_bf16(vf, pf, of[n], 0, 0, 0);
            }
        }
        __builtin_amdgcn_s_setprio(0);
    }

    float inv = 1.f / l;
    ushort* ob = O + ((size_t)(b * S) + qr0 + fr) * rs + h * 128 + fq * 4;
#pragma unroll
    for (int n = 0; n < 8; ++n) {
        uint2 o2;
        o2.x = cvt_pk_bf16(of[n][0] * inv, of[n][1] * inv);
        o2.y = cvt_pk_bf16(of[n][2] * inv, of[n][3] * inv);
        *reinterpret_cast<uint2*>(ob + n * 16) = o2;
    }
}

// ---------------- launch ----------------
extern "C" void kernel_launch(void* const* d_in, const int* in_sizes, int n_in,
                              void* d_out, int out_size, void* d_ws, size_t ws_size,
                              hipStream_t stream) {
    constexpr int B = 2, S = 2048, HID = 2048, H = 16;
    constexpr int M = B * S;
    const float qscale = 0.08838834764831845f * 1.4426950408889634f;  // scale*log2e

    const float* x  = (const float*)d_in[0];
    const float* wq = (const float*)d_in[1];
    const float* wk = (const float*)d_in[2];
    const float* wv = (const float*)d_in[3];
    const float* wo = (const float*)d_in[4];
    float* out = (float*)d_out;

    char* ws = (char*)d_ws;
    ushort* xb  = (ushort*)(ws);                    // [4096][2048] bf16; reused as attn out
    ushort* wqb = (ushort*)(ws + 16777216);         // wq,wk,wv casts contiguous (24 MB)
    ushort* wvb = (ushort*)(ws + 33554432);
    ushort* qb  = (ushort*)(ws + 41943040);         // q,k contiguous (32 MB)
    ushort* kb  = (ushort*)(ws + 58720256);
    ushort* vtb = (ushort*)(ws + 75497472);         // V^T [2048][4096] (16 MB)

    const int XN = M * HID;
    const int WN = HID * HID;
    const int n4x = XN / 4, n4w = WN / 4;

    // fused cast: x -> xb, {wq,wk,wv} -> wqb (contiguous)
    cast4_kernel<<<(n4x + 3 * n4w) / 256, 256, 0, stream>>>(x, wq, wk, wv, xb, wqb, n4x, n4w);

    // Q,K projection: pipelined 256-tile GEMM; Q pre-scaled by scale*log2e
    dim3 gq(2 * HID / 256, M / 256);   // (16, 16) = 256 blocks x 512 threads
    gemm256_kernel<<<gq, 512, 0, stream>>>(xb, wqb, qb, M, HID, HID, qscale);

    // V^T projection via pipelined 128-tile GEMM
    dim3 gv(M / 128, HID / 128);       // (32, 16) = 512 blocks x 256 threads
    gemm128p_kernel<ushort><<<gv, 256, 0, stream>>>(wvb, xb, vtb, HID, M, HID);

    dim3 ga(H * B, S / 128);           // (32, 16) = 512 blocks x 512 threads
    attn_kernel<<<ga, 512, 0, stream>>>(qb, kb, vtb, xb, S, HID);

    cast_kernel<<<WN / 4 / 256, 256, 0, stream>>>(wo, wqb, WN / 4);
    dim3 gg(HID / 128, M / 128);       // (16, 32) = 512 blocks x 256 threads
    gemm128p_kernel<float><<<gg, 256, 0, stream>>>(xb, wqb, out, M, HID, HID);
}